// Round 2
// baseline (232.366 us; speedup 1.0000x reference)
//
#include <hip/hip_runtime.h>
#include <hip/hip_bf16.h>
#include <math.h>

// Problem constants
#define BB 2
#define SS 2048
#define DD 1024
#define HH 16
#define HD 64

typedef __attribute__((ext_vector_type(8))) _Float16 f16x8;
typedef __attribute__((ext_vector_type(2))) __fp16 fp16x2;
typedef __attribute__((ext_vector_type(8))) unsigned short u16x8;
typedef __attribute__((ext_vector_type(4))) float f32x4;
typedef __attribute__((ext_vector_type(4))) unsigned short u16x4;

__device__ __forceinline__ unsigned short hbits(_Float16 h) {
    union { _Float16 h; unsigned short s; } u; u.h = h; return u.s;
}

// XOR-swizzled 64x64 fp16 tile: off(row, col) = row*64 + ((col>>3 ^ row&7)<<3) + col&7
__device__ __forceinline__ int swz(int row, int grp) {
    return (row << 6) + (((grp) ^ (row & 7)) << 3);
}

__device__ __forceinline__ float fexp2(float x) {
#if __has_builtin(__builtin_amdgcn_exp2f)
    return __builtin_amdgcn_exp2f(x);
#else
    return exp2f(x);
#endif
}

__device__ __forceinline__ u16x4 pack4(float p0, float p1, float p2, float p3) {
#if __has_builtin(__builtin_amdgcn_cvt_pkrtz)
    union { fp16x2 h[2]; u16x4 u; } pu;
    pu.h[0] = __builtin_amdgcn_cvt_pkrtz(p0, p1);
    pu.h[1] = __builtin_amdgcn_cvt_pkrtz(p2, p3);
    return pu.u;
#else
    u16x4 r;
    r[0] = hbits((_Float16)p0); r[1] = hbits((_Float16)p1);
    r[2] = hbits((_Float16)p2); r[3] = hbits((_Float16)p3);
    return r;
#endif
}

// async global->LDS 16B/lane: lds dest = wave-uniform base + lane*16.
__device__ __forceinline__ void gload_lds16(const unsigned short* g, unsigned short* l) {
#if __has_builtin(__builtin_amdgcn_global_load_lds)
    auto gp = (const __attribute__((address_space(1))) unsigned int*)(uintptr_t)g;
    auto lp = (__attribute__((address_space(3))) unsigned int*)(uintptr_t)l;
    __builtin_amdgcn_global_load_lds(gp, lp, 16, 0, 0);
#else
    *(u16x8*)(l + (threadIdx.x & 63) * 8) = *(const u16x8*)g;
#endif
}

// ---------------------------------------------------------------------------
// Prepass: X -> fp16 (same layout); W -> fp16 transposed rows WT[n][k].
// ---------------------------------------------------------------------------
__global__ __launch_bounds__(256) void prep_convert(
    const float* __restrict__ X,
    const float* __restrict__ Wq, const float* __restrict__ Wk,
    const float* __restrict__ Wv, const float* __restrict__ Wo,
    unsigned short* __restrict__ Xh, unsigned short* __restrict__ WT)
{
    __shared__ __align__(16) unsigned short LT[64 * 68];
    const int bid = blockIdx.x;
    const int tid = threadIdx.x;

    if (bid < 2048) {
        const int base = bid * 2048 + tid * 8;
        float4 a = *(const float4*)&X[base];
        float4 b = *(const float4*)&X[base + 4];
        u16x8 o;
        o[0] = hbits((_Float16)a.x); o[1] = hbits((_Float16)a.y);
        o[2] = hbits((_Float16)a.z); o[3] = hbits((_Float16)a.w);
        o[4] = hbits((_Float16)b.x); o[5] = hbits((_Float16)b.y);
        o[6] = hbits((_Float16)b.z); o[7] = hbits((_Float16)b.w);
        *(u16x8*)&Xh[base] = o;
        return;
    }

    const int t = bid - 2048;
    const float* src;
    size_t stride;
    int outRow0, kcol0;
    if (t < 768) {
        const int nt = t >> 4, ktile = t & 15;
        const int sel = nt >> 4, hh = nt & 15;
        const float* Ws = (sel == 0) ? Wq : ((sel == 1) ? Wk : Wv);
        src = Ws + (size_t)hh * (DD * HD) + (size_t)ktile * 64 * HD;
        stride = HD;
        outRow0 = nt * 64;
        kcol0 = ktile * 64;
    } else {
        const int tt = t - 768;
        const int nt = tt & 15, ktile = tt >> 4;
        src = Wo + (size_t)ktile * 64 * DD + nt * 64;
        stride = DD;
        outRow0 = 3072 + nt * 64;
        kcol0 = ktile * 64;
    }

    const int e = tid & 63, dq = tid >> 6;
#pragma unroll
    for (int p = 0; p < 16; p++) {
        const int dl = p * 4 + dq;
        LT[e * 68 + dl] = hbits((_Float16)src[(size_t)dl * stride + e]);
    }
    __syncthreads();
    const int eo = tid >> 2, d16 = (tid & 3) * 16;
#pragma unroll
    for (int j = 0; j < 4; j++) {
        *(ushort4*)&WT[(size_t)(outRow0 + eo) * DD + kcol0 + d16 + j * 4] =
            *(const ushort4*)&LT[eo * 68 + d16 + j * 4];
    }
}

// ---------------------------------------------------------------------------
// fp16 MFMA QKV GEMM: 128x128 tile, BK=32, 256 threads (4 waves, 2x2),
// double-buffered global_load_lds. 32 KiB LDS -> 3 blocks/CU resident
// (768 blocks = 3 per CU exactly, zero dispatch tail, 12 waves/CU): the
// per-iter vmcnt drain at the barrier overlaps with the other 2 blocks'
// compute (m114 wave-level overlap).
// ---------------------------------------------------------------------------
#define GBM 128
#define GBN 128
#define GBK 64
#define NKT (DD / GBK)   // 16 (out_gemm)
#define QBK 32
#define QNKT (DD / QBK)  // 32 (qkv_gemm)

__global__ __launch_bounds__(256) void qkv_gemm(
    const unsigned short* __restrict__ Xh, const unsigned short* __restrict__ WT,
    const float* __restrict__ bq, const float* __restrict__ bk,
    const float* __restrict__ bv,
    unsigned short* __restrict__ qh, unsigned short* __restrict__ kh,
    unsigned short* __restrict__ vTs, unsigned int* __restrict__ kc2)
{
    // 8 chunks of 512 shorts per buffer; chunk c = rows c*16 + l15, k = quad*8.
    __shared__ __align__(16) unsigned short As[2][8 * 512];
    __shared__ __align__(16) unsigned short Bs[2][8 * 512];

    const int tid = threadIdx.x;
    const int m0 = blockIdx.y * GBM;
    const int n0 = blockIdx.x * GBN;
    const int lane = tid & 63;
    const int w = tid >> 6;
    const int wm = w & 1, wn = w >> 1;
    const int l15 = lane & 15, quad = lane >> 4;

    // staging source offset for chunk c = p*4 + w (p = 0,1)
    int g_off[2];
#pragma unroll
    for (int p = 0; p < 2; p++) {
        const int c = p * 4 + w;
        g_off[p] = (c * 16 + l15) * DD + quad * 8;
    }

    f32x4 acc[4][4];
#pragma unroll
    for (int i = 0; i < 4; i++)
#pragma unroll
        for (int j = 0; j < 4; j++) acc[i][j] = (f32x4){0.f, 0.f, 0.f, 0.f};

    const unsigned short* Abase = Xh + (size_t)m0 * DD;
    const unsigned short* Bbase = WT + (size_t)n0 * DD;

    // prologue: DMA tile 0 into buffer 0 (4 loads/thread)
#pragma unroll
    for (int p = 0; p < 2; p++) {
        gload_lds16(Abase + g_off[p], &As[0][(p * 4 + w) * 512]);
        gload_lds16(Bbase + g_off[p], &Bs[0][(p * 4 + w) * 512]);
    }

    for (int it = 0; it < QNKT; it++) {
        const int cur = it & 1;
        __syncthreads();   // drains DMA(it); all waves done reading buf[cur^1]
        if (it + 1 < QNKT) {
            const int kt2 = (it + 1) * QBK;
#pragma unroll
            for (int p = 0; p < 2; p++) {
                gload_lds16(Abase + g_off[p] + kt2, &As[cur ^ 1][(p * 4 + w) * 512]);
                gload_lds16(Bbase + g_off[p] + kt2, &Bs[cur ^ 1][(p * 4 + w) * 512]);
            }
        }
        f16x8 af[4], bf[4];
#pragma unroll
        for (int i = 0; i < 4; i++) {
            af[i] = *(const f16x8*)&As[cur][(wm * 4 + i) * 512 + lane * 8];
            bf[i] = *(const f16x8*)&Bs[cur][(wn * 4 + i) * 512 + lane * 8];
        }
#pragma unroll
        for (int ns = 0; ns < 4; ns++)
#pragma unroll
            for (int ms = 0; ms < 4; ms++)
                acc[ms][ns] = __builtin_amdgcn_mfma_f32_16x16x32_f16(
                    af[ms], bf[ns], acc[ms][ns], 0, 0, 0);
    }

    // epilogue: bias + fp16; q linear [B,H,S,HD]; k AND v pre-swizzled tiles
    // (v transposed: offset(key,e) = tile*4096 + swz(e, key>>3) + (key&7)).
    const int sel = n0 >> 10;
    const int hw = ((n0 + wn * 64) >> 6) & 15;
    const int bblk = m0 >> 11;
    const float* bias = (sel == 0) ? bq : ((sel == 1) ? bk : bv);
    const size_t bh_base = ((size_t)bblk * HH + hw) * SS * HD;
    float wmx = 0.0f;
#pragma unroll
    for (int ms = 0; ms < 4; ms++) {
#pragma unroll
        for (int rr = 0; rr < 4; rr++) {
            const int m = m0 + wm * 64 + ms * 16 + quad * 4 + rr;
            const int s = m & (SS - 1);
            const int s63 = s & 63;
            float v2 = 0.0f;
#pragma unroll
            for (int ns = 0; ns < 4; ns++) {
                const int e = ns * 16 + l15;
                const float val = acc[ms][ns][rr] + bias[hw * HD + e];
                if (sel == 0) {
                    qh[bh_base + (size_t)s * HD + e] = hbits((_Float16)val);
                } else if (sel == 1) {
                    v2 = fmaf(val, val, v2);
                    const size_t kofs = bh_base + (size_t)(s >> 6) * 4096
                                      + swz(s63, e >> 3) + (e & 7);
                    kh[kofs] = hbits((_Float16)val);
                } else {
                    const size_t vofs = bh_base + (size_t)(s >> 6) * 4096
                                      + swz(e, s63 >> 3) + (s63 & 7);
                    vTs[vofs] = hbits((_Float16)val);
                }
            }
            if (sel == 1) {
                v2 += __shfl_xor(v2, 1);
                v2 += __shfl_xor(v2, 2);
                v2 += __shfl_xor(v2, 4);
                v2 += __shfl_xor(v2, 8);
                wmx = fmaxf(wmx, v2);
            }
        }
    }
    if (sel == 1) {
        wmx = fmaxf(wmx, __shfl_xor(wmx, 16));
        wmx = fmaxf(wmx, __shfl_xor(wmx, 32));
        if (lane == 0)
            atomicMax(&kc2[bblk * HH + hw], __float_as_uint(wmx));
    }
}

__global__ __launch_bounds__(256) void out_gemm(
    const unsigned short* __restrict__ Ctxh, const unsigned short* __restrict__ WoT,
    const float* __restrict__ bo, float* __restrict__ out)
{
    __shared__ __align__(16) unsigned short As[2][16 * 512];
    __shared__ __align__(16) unsigned short Bs[2][16 * 512];

    const int tid = threadIdx.x;
    const int m0 = blockIdx.y * GBM;
    const int n0 = blockIdx.x * GBN;
    const int lane = tid & 63;
    const int w = tid >> 6;
    const int wm = w & 1, wn = w >> 1;
    const int l15 = lane & 15, quad = lane >> 4;

    int g_off[4];
#pragma unroll
    for (int p = 0; p < 4; p++) {
        const int c = p * 4 + w;
        g_off[p] = ((c >> 1) * 16 + (lane & 15)) * DD + (c & 1) * 32 + (lane >> 4) * 8;
    }

    f32x4 acc[4][4];
#pragma unroll
    for (int i = 0; i < 4; i++)
#pragma unroll
        for (int j = 0; j < 4; j++) acc[i][j] = (f32x4){0.f, 0.f, 0.f, 0.f};

    const unsigned short* Abase = Ctxh + (size_t)m0 * DD;
    const unsigned short* Bbase = WoT + (size_t)n0 * DD;

#pragma unroll
    for (int p = 0; p < 4; p++) {
        gload_lds16(Abase + g_off[p], &As[0][(p * 4 + w) * 512]);
        gload_lds16(Bbase + g_off[p], &Bs[0][(p * 4 + w) * 512]);
    }

    for (int it = 0; it < NKT; it++) {
        const int cur = it & 1;
        __syncthreads();
        if (it + 1 < NKT) {
            const int kt2 = (it + 1) * GBK;
#pragma unroll
            for (int p = 0; p < 4; p++) {
                gload_lds16(Abase + g_off[p] + kt2, &As[cur ^ 1][(p * 4 + w) * 512]);
                gload_lds16(Bbase + g_off[p] + kt2, &Bs[cur ^ 1][(p * 4 + w) * 512]);
            }
        }
#pragma unroll
        for (int ks = 0; ks < 2; ks++) {
            f16x8 af[4], bf[4];
#pragma unroll
            for (int i = 0; i < 4; i++) {
                af[i] = *(const f16x8*)&As[cur][((wm * 4 + i) * 2 + ks) * 512 + lane * 8];
                bf[i] = *(const f16x8*)&Bs[cur][((wn * 4 + i) * 2 + ks) * 512 + lane * 8];
            }
#pragma unroll
            for (int ns = 0; ns < 4; ns++)
#pragma unroll
                for (int ms = 0; ms < 4; ms++)
                    acc[ms][ns] = __builtin_amdgcn_mfma_f32_16x16x32_f16(
                        af[ms], bf[ns], acc[ms][ns], 0, 0, 0);
        }
    }

#pragma unroll
    for (int ms = 0; ms < 4; ms++) {
#pragma unroll
        for (int rr = 0; rr < 4; rr++) {
            const size_t m = (size_t)(m0 + wm * 64 + ms * 16 + quad * 4 + rr);
#pragma unroll
            for (int ns = 0; ns < 4; ns++) {
                const int n = n0 + wn * 64 + ns * 16 + l15;
                out[m * DD + n] = acc[ms][ns][rr] + bo[n];
            }
        }
    }
}

// ---------------------------------------------------------------------------
// fp16 MFMA flash attention (S^T), fixed-m softmax, DOUBLE-BUFFERED DMA from
// pre-swizzled K / V^T global tiles (one barrier per tile), l via ones-MFMA.
// ---------------------------------------------------------------------------
#define TQB 128
#define TKB 64
#define NT (SS / TKB)    // 32
#define C1 0.1803368801111204f   // 0.125 * log2(e)

__global__ __launch_bounds__(256) void attn_mfma(
    const unsigned short* __restrict__ qh, const unsigned short* __restrict__ kh,
    const unsigned short* __restrict__ vTs, const unsigned int* __restrict__ kc2,
    unsigned short* __restrict__ ctxh)
{
    __shared__ __align__(16) unsigned short KL [2][TKB * 64];
    __shared__ __align__(16) unsigned short VtL[2][HD * 64];
    __shared__ __align__(16) unsigned short PsL[4][32 * 64];

    const int tid  = threadIdx.x;
    const int lane = tid & 63;
    const int w    = tid >> 6;
    const int l15  = lane & 15;
    const int quad = lane >> 4;
    const int bh   = blockIdx.y;
    const int q0   = blockIdx.x * TQB;

    const float kfac = sqrtf(__uint_as_float(kc2[bh])) * 1.01f * C1;

    // Q B-frags (lane l15 = q-row, quad = d-octet) + per-lane fixed-m bound
    f16x8 qf[2][2];
    float M2[2];
#pragma unroll
    for (int msub = 0; msub < 2; msub++) {
        const unsigned short* qrow =
            qh + ((size_t)bh * SS + q0 + w * 32 + msub * 16 + l15) * HD;
        float nq2 = 0.0f;
#pragma unroll
        for (int dstep = 0; dstep < 2; dstep++) {
            qf[msub][dstep] = *(const f16x8*)&qrow[dstep * 32 + quad * 8];
#pragma unroll
            for (int j = 0; j < 8; j++) {
                const float x = (float)qf[msub][dstep][j];
                nq2 = fmaf(x, x, nq2);
            }
        }
        nq2 += __shfl_xor(nq2, 16);
        nq2 += __shfl_xor(nq2, 32);
        M2[msub] = sqrtf(nq2) * kfac;
    }

    f16x8 ones;
#pragma unroll
    for (int j = 0; j < 8; j++) ones[j] = (_Float16)1.0f;

    f32x4 o[2][4], lones[2];
#pragma unroll
    for (int ms = 0; ms < 2; ms++) {
        lones[ms] = (f32x4){0.f, 0.f, 0.f, 0.f};
#pragma unroll
        for (int e = 0; e < 4; e++) o[ms][e] = (f32x4){0.f, 0.f, 0.f, 0.f};
    }

    const unsigned short* kb0 = kh  + (size_t)bh * SS * HD;
    const unsigned short* vb0 = vTs + (size_t)bh * SS * HD;

    // prologue: DMA tile 0 into buffer 0
    gload_lds16(kb0 + tid * 8,        &KL [0][w * 512]);
    gload_lds16(kb0 + 2048 + tid * 8, &KL [0][2048 + w * 512]);
    gload_lds16(vb0 + tid * 8,        &VtL[0][w * 512]);
    gload_lds16(vb0 + 2048 + tid * 8, &VtL[0][2048 + w * 512]);

    for (int t = 0; t < NT; t++) {
        const int cur = t & 1;
        __syncthreads();   // drains DMA(t); all waves done with buf[cur^1]
        if (t + 1 < NT) {
            const unsigned short* kb = kb0 + (size_t)(t + 1) * 4096;
            const unsigned short* vb = vb0 + (size_t)(t + 1) * 4096;
            gload_lds16(kb + tid * 8,        &KL [cur ^ 1][w * 512]);
            gload_lds16(kb + 2048 + tid * 8, &KL [cur ^ 1][2048 + w * 512]);
            gload_lds16(vb + tid * 8,        &VtL[cur ^ 1][w * 512]);
            gload_lds16(vb + 2048 + tid * 8, &VtL[cur ^ 1][2048 + w * 512]);
        }

        // ---- scores TRANSPOSED: S^T = K·Q^T; C/D row = key, col = q = l15
        f32x4 sc[2][4];
#pragma unroll
        for (int ksub = 0; ksub < 4; ksub++) {
            const int row = ksub * 16 + l15;
            f16x8 k0 = *(const f16x8*)&KL[cur][swz(row, quad)];
            f16x8 k1 = *(const f16x8*)&KL[cur][swz(row, 4 + quad)];
#pragma unroll
            for (int msub = 0; msub < 2; msub++) {
                f32x4 a = (f32x4){0.f, 0.f, 0.f, 0.f};
                a = __builtin_amdgcn_mfma_f32_16x16x32_f16(k0, qf[msub][0], a, 0, 0, 0);
                a = __builtin_amdgcn_mfma_f32_16x16x32_f16(k1, qf[msub][1], a, 0, 0, 0);
                sc[msub][ksub] = a;
            }
        }

        // ---- fixed-m softmax (per-lane q = l15), packed f16 P
#pragma unroll
        for (int msub = 0; msub < 2; msub++) {
            const int prow = msub * 16 + l15;
#pragma unroll
            for (int ksub = 0; ksub < 4; ksub++) {
                const float p0 = fexp2(fmaf(sc[msub][ksub][0], C1, -M2[msub]));
                const float p1 = fexp2(fmaf(sc[msub][ksub][1], C1, -M2[msub]));
                const float p2 = fexp2(fmaf(sc[msub][ksub][2], C1, -M2[msub]));
                const float p3 = fexp2(fmaf(sc[msub][ksub][3], C1, -M2[msub]));
                *(u16x4*)&PsL[w][swz(prow, ksub * 2 + (quad >> 1)) + (quad & 1) * 4] =
                    pack4(p0, p1, p2, p3);
            }
        }

        // ---- PV + l via ones-MFMA (PsL wave-private: no barrier)
#pragma unroll
        for (int kj = 0; kj < 2; kj++) {
            f16x8 pa[2];
#pragma unroll
            for (int msub = 0; msub < 2; msub++)
                pa[msub] = *(const f16x8*)&PsL[w][swz(msub * 16 + l15, kj * 4 + quad)];
            lones[0] = __builtin_amdgcn_mfma_f32_16x16x32_f16(pa[0], ones, lones[0], 0, 0, 0);
            lones[1] = __builtin_amdgcn_mfma_f32_16x16x32_f16(pa[1], ones, lones[1], 0, 0, 0);
#pragma unroll
            for (int esub = 0; esub < 4; esub++) {
                f16x8 vr = *(const f16x8*)&VtL[cur][swz(esub * 16 + l15, kj * 4 + quad)];
                o[0][esub] = __builtin_amdgcn_mfma_f32_16x16x32_f16(pa[0], vr, o[0][esub], 0, 0, 0);
                o[1][esub] = __builtin_amdgcn_mfma_f32_16x16x32_f16(pa[1], vr, o[1][esub], 0, 0, 0);
            }
        }
    }

    // ---- epilogue: l sits in the same C-layout rows as o — no shuffles
    const int b = bh >> 4;
    const int h = bh & 15;
#pragma unroll
    for (int msub = 0; msub < 2; msub++) {
#pragma unroll
        for (int rr = 0; rr < 4; rr++) {
            const float linv = 1.0f / lones[msub][rr];
            const int row = q0 + w * 32 + msub * 16 + quad * 4 + rr;
#pragma unroll
            for (int esub = 0; esub < 4; esub++) {
                ctxh[((size_t)b * SS + row) * DD + h * HD + esub * 16 + l15] =
                    hbits((_Float16)(o[msub][esub][rr] * linv));
            }
        }
    }
}

// ---------------------------------------------------------------------------
extern "C" void kernel_launch(void* const* d_in, const int* in_sizes, int n_in,
                              void* d_out, int out_size, void* d_ws, size_t ws_size,
                              hipStream_t stream) {
    const float* X  = (const float*)d_in[0];
    const float* Wq = (const float*)d_in[1];
    const float* bq = (const float*)d_in[2];
    const float* Wk = (const float*)d_in[3];
    const float* bk = (const float*)d_in[4];
    const float* Wv = (const float*)d_in[5];
    const float* bv = (const float*)d_in[6];
    const float* Wo = (const float*)d_in[7];
    const float* bo = (const float*)d_in[8];
    float* out = (float*)d_out;

    // ws: Xh | WT(4096 rows) | qh | kh(swz) | vTs(swz) | ctxh | kc2
    const size_t NB2 = (size_t)4096 * 1024 * 2;   // 8388608 B
    unsigned char* w8 = (unsigned char*)d_ws;
    unsigned short* Xh   = (unsigned short*)(w8);
    unsigned short* WT   = (unsigned short*)(w8 + NB2);
    unsigned short* qh   = (unsigned short*)(w8 + 2 * NB2);
    unsigned short* kh   = (unsigned short*)(w8 + 3 * NB2);
    unsigned short* vTs  = (unsigned short*)(w8 + 4 * NB2);
    unsigned short* ctxh = (unsigned short*)(w8 + 5 * NB2);
    unsigned int*   kc2  = (unsigned int*)(w8 + 6 * NB2);
    unsigned short* WoT  = WT + (size_t)3072 * 1024;

    (void)hipMemsetAsync(kc2, 0, BB * HH * sizeof(unsigned int), stream);

    // 0) convert X + transpose/convert weights to fp16
    prep_convert<<<dim3(3072), 256, 0, stream>>>(X, Wq, Wk, Wv, Wo, Xh, WT);

    // 1) fused QKV projection (fp16 MFMA, BK=32, 3 blocks/CU fully resident)
    qkv_gemm<<<dim3(3072 / GBN, 4096 / GBM), 256, 0, stream>>>(
        Xh, WT, bq, bk, bv, qh, kh, vTs, kc2);

    // 2) MFMA flash attention (S^T, fixed-m softmax, dbuf DMA)
    attn_mfma<<<dim3(SS / TQB, BB * HH), 256, 0, stream>>>(qh, kh, vTs, kc2, ctxh);

    // 3) output projection (fp16 MFMA, dbuf DMA)
    out_gemm<<<dim3(1024 / GBN, 4096 / GBM), 256, 0, stream>>>(ctxh, WoT, bo, out);
}

// Round 3
// 220.533 us; speedup vs baseline: 1.0537x; 1.0537x over previous
//
#include <hip/hip_runtime.h>
#include <hip/hip_bf16.h>
#include <math.h>

// Problem constants
#define BB 2
#define SS 2048
#define DD 1024
#define HH 16
#define HD 64

typedef __attribute__((ext_vector_type(8))) _Float16 f16x8;
typedef __attribute__((ext_vector_type(2))) __fp16 fp16x2;
typedef __attribute__((ext_vector_type(8))) unsigned short u16x8;
typedef __attribute__((ext_vector_type(4))) float f32x4;
typedef __attribute__((ext_vector_type(4))) unsigned short u16x4;

__device__ __forceinline__ unsigned short hbits(_Float16 h) {
    union { _Float16 h; unsigned short s; } u; u.h = h; return u.s;
}

// XOR-swizzled 64x64 fp16 tile: off(row, col) = row*64 + ((col>>3 ^ row&7)<<3) + col&7
__device__ __forceinline__ int swz(int row, int grp) {
    return (row << 6) + (((grp) ^ (row & 7)) << 3);
}

__device__ __forceinline__ float fexp2(float x) {
#if __has_builtin(__builtin_amdgcn_exp2f)
    return __builtin_amdgcn_exp2f(x);
#else
    return exp2f(x);
#endif
}

__device__ __forceinline__ u16x4 pack4(float p0, float p1, float p2, float p3) {
#if __has_builtin(__builtin_amdgcn_cvt_pkrtz)
    union { fp16x2 h[2]; u16x4 u; } pu;
    pu.h[0] = __builtin_amdgcn_cvt_pkrtz(p0, p1);
    pu.h[1] = __builtin_amdgcn_cvt_pkrtz(p2, p3);
    return pu.u;
#else
    u16x4 r;
    r[0] = hbits((_Float16)p0); r[1] = hbits((_Float16)p1);
    r[2] = hbits((_Float16)p2); r[3] = hbits((_Float16)p3);
    return r;
#endif
}

// async global->LDS 16B/lane: lds dest = wave-uniform base + lane*16.
__device__ __forceinline__ void gload_lds16(const unsigned short* g, unsigned short* l) {
#if __has_builtin(__builtin_amdgcn_global_load_lds)
    auto gp = (const __attribute__((address_space(1))) unsigned int*)(uintptr_t)g;
    auto lp = (__attribute__((address_space(3))) unsigned int*)(uintptr_t)l;
    __builtin_amdgcn_global_load_lds(gp, lp, 16, 0, 0);
#else
    *(u16x8*)(l + (threadIdx.x & 63) * 8) = *(const u16x8*)g;
#endif
}

// Counted-vmcnt barriers: single asm blob so no load can slip between the
// wait and the barrier. Steady-state never drains vmcnt to 0 (T4).
__device__ __forceinline__ void wait4_barrier() {
    asm volatile("s_waitcnt vmcnt(4) lgkmcnt(0)\n\ts_barrier" ::: "memory");
}
__device__ __forceinline__ void wait8_barrier() {
    asm volatile("s_waitcnt vmcnt(8) lgkmcnt(0)\n\ts_barrier" ::: "memory");
}
__device__ __forceinline__ void wait0_barrier() {
    asm volatile("s_waitcnt vmcnt(0) lgkmcnt(0)\n\ts_barrier" ::: "memory");
}

// ---------------------------------------------------------------------------
// Prepass: X -> fp16 (same layout); W -> fp16 transposed rows WT[n][k].
// ---------------------------------------------------------------------------
__global__ __launch_bounds__(256) void prep_convert(
    const float* __restrict__ X,
    const float* __restrict__ Wq, const float* __restrict__ Wk,
    const float* __restrict__ Wv, const float* __restrict__ Wo,
    unsigned short* __restrict__ Xh, unsigned short* __restrict__ WT)
{
    __shared__ __align__(16) unsigned short LT[64 * 68];
    const int bid = blockIdx.x;
    const int tid = threadIdx.x;

    if (bid < 2048) {
        const int base = bid * 2048 + tid * 8;
        float4 a = *(const float4*)&X[base];
        float4 b = *(const float4*)&X[base + 4];
        u16x8 o;
        o[0] = hbits((_Float16)a.x); o[1] = hbits((_Float16)a.y);
        o[2] = hbits((_Float16)a.z); o[3] = hbits((_Float16)a.w);
        o[4] = hbits((_Float16)b.x); o[5] = hbits((_Float16)b.y);
        o[6] = hbits((_Float16)b.z); o[7] = hbits((_Float16)b.w);
        *(u16x8*)&Xh[base] = o;
        return;
    }

    const int t = bid - 2048;
    const float* src;
    size_t stride;
    int outRow0, kcol0;
    if (t < 768) {
        const int nt = t >> 4, ktile = t & 15;
        const int sel = nt >> 4, hh = nt & 15;
        const float* Ws = (sel == 0) ? Wq : ((sel == 1) ? Wk : Wv);
        src = Ws + (size_t)hh * (DD * HD) + (size_t)ktile * 64 * HD;
        stride = HD;
        outRow0 = nt * 64;
        kcol0 = ktile * 64;
    } else {
        const int tt = t - 768;
        const int nt = tt & 15, ktile = tt >> 4;
        src = Wo + (size_t)ktile * 64 * DD + nt * 64;
        stride = DD;
        outRow0 = 3072 + nt * 64;
        kcol0 = ktile * 64;
    }

    const int e = tid & 63, dq = tid >> 6;
#pragma unroll
    for (int p = 0; p < 16; p++) {
        const int dl = p * 4 + dq;
        LT[e * 68 + dl] = hbits((_Float16)src[(size_t)dl * stride + e]);
    }
    __syncthreads();
    const int eo = tid >> 2, d16 = (tid & 3) * 16;
#pragma unroll
    for (int j = 0; j < 4; j++) {
        *(ushort4*)&WT[(size_t)(outRow0 + eo) * DD + kcol0 + d16 + j * 4] =
            *(const ushort4*)&LT[eo * 68 + d16 + j * 4];
    }
}

// ---------------------------------------------------------------------------
// fp16 MFMA QKV GEMM: 128x128 tile, BK=32, 256 threads (4 waves, 2x2),
// TRIPLE-buffered LDS with depth-2 DMA prefetch + counted vmcnt (T3/T4):
// one raw s_barrier per iter, steady-state waits vmcnt(4) (tile t+1 landed,
// tile t+2 in flight) -> L2/HBM latency covered by ~2 full iterations.
// 48 KiB LDS -> 3 blocks/CU (768 blocks = 3/CU exactly, no tail).
// ---------------------------------------------------------------------------
#define GBM 128
#define GBN 128
#define GBK 64
#define NKT (DD / GBK)   // 16 (out_gemm)
#define QBK 32
#define QNKT (DD / QBK)  // 32 (qkv_gemm)

__global__ __launch_bounds__(256) void qkv_gemm(
    const unsigned short* __restrict__ Xh, const unsigned short* __restrict__ WT,
    const float* __restrict__ bq, const float* __restrict__ bk,
    const float* __restrict__ bv,
    unsigned short* __restrict__ qh, unsigned short* __restrict__ kh,
    unsigned short* __restrict__ vTs, unsigned int* __restrict__ kc2)
{
    // 8 chunks of 512 shorts per buffer; chunk c = rows c*16 + l15, k = quad*8.
    __shared__ __align__(16) unsigned short As[3][8 * 512];
    __shared__ __align__(16) unsigned short Bs[3][8 * 512];

    const int tid = threadIdx.x;
    const int m0 = blockIdx.y * GBM;
    const int n0 = blockIdx.x * GBN;
    const int lane = tid & 63;
    const int w = tid >> 6;
    const int wm = w & 1, wn = w >> 1;
    const int l15 = lane & 15, quad = lane >> 4;

    // staging source offset for chunk c = p*4 + w (p = 0,1)
    int g_off[2];
#pragma unroll
    for (int p = 0; p < 2; p++) {
        const int c = p * 4 + w;
        g_off[p] = (c * 16 + l15) * DD + quad * 8;
    }

    f32x4 acc[4][4];
#pragma unroll
    for (int i = 0; i < 4; i++)
#pragma unroll
        for (int j = 0; j < 4; j++) acc[i][j] = (f32x4){0.f, 0.f, 0.f, 0.f};

    const unsigned short* Abase = Xh + (size_t)m0 * DD;
    const unsigned short* Bbase = WT + (size_t)n0 * DD;

    // prologue: DMA tiles 0,1 into buffers 0,1; full drain once (immune to
    // any stray hoisted vmem), then barrier.
#pragma unroll
    for (int p = 0; p < 2; p++) {
        gload_lds16(Abase + g_off[p], &As[0][(p * 4 + w) * 512]);
        gload_lds16(Bbase + g_off[p], &Bs[0][(p * 4 + w) * 512]);
    }
#pragma unroll
    for (int p = 0; p < 2; p++) {
        gload_lds16(Abase + g_off[p] + QBK, &As[1][(p * 4 + w) * 512]);
        gload_lds16(Bbase + g_off[p] + QBK, &Bs[1][(p * 4 + w) * 512]);
    }
    wait0_barrier();

    int cur = 0, pre = 2;
    for (int t = 0; t < QNKT; t++) {
        // issue DMA(t+2) first: overwrites buf[(t-1)%3], whose reads were all
        // consumed by MFMAs before the previous barrier.
        if (t + 2 < QNKT) {
            const int kt2 = (t + 2) * QBK;
#pragma unroll
            for (int p = 0; p < 2; p++) {
                gload_lds16(Abase + g_off[p] + kt2, &As[pre][(p * 4 + w) * 512]);
                gload_lds16(Bbase + g_off[p] + kt2, &Bs[pre][(p * 4 + w) * 512]);
            }
        }
        f16x8 af[4], bf[4];
#pragma unroll
        for (int i = 0; i < 4; i++) {
            af[i] = *(const f16x8*)&As[cur][(wm * 4 + i) * 512 + lane * 8];
            bf[i] = *(const f16x8*)&Bs[cur][(wn * 4 + i) * 512 + lane * 8];
        }
#pragma unroll
        for (int ns = 0; ns < 4; ns++)
#pragma unroll
            for (int ms = 0; ms < 4; ms++)
                acc[ms][ns] = __builtin_amdgcn_mfma_f32_16x16x32_f16(
                    af[ms], bf[ns], acc[ms][ns], 0, 0, 0);
        // trailing: guarantee tile t+1 landed CU-wide; keep t+2 in flight.
        if (t < QNKT - 2)       wait4_barrier();
        else if (t == QNKT - 2) wait0_barrier();
        cur = (cur == 2) ? 0 : cur + 1;
        pre = (pre == 2) ? 0 : pre + 1;
    }

    // epilogue: bias + fp16; q linear [B,H,S,HD]; k AND v pre-swizzled tiles
    // (v transposed: offset(key,e) = tile*4096 + swz(e, key>>3) + (key&7)).
    const int sel = n0 >> 10;
    const int hw = ((n0 + wn * 64) >> 6) & 15;
    const int bblk = m0 >> 11;
    const float* bias = (sel == 0) ? bq : ((sel == 1) ? bk : bv);
    const size_t bh_base = ((size_t)bblk * HH + hw) * SS * HD;
    float wmx = 0.0f;
#pragma unroll
    for (int ms = 0; ms < 4; ms++) {
#pragma unroll
        for (int rr = 0; rr < 4; rr++) {
            const int m = m0 + wm * 64 + ms * 16 + quad * 4 + rr;
            const int s = m & (SS - 1);
            const int s63 = s & 63;
            float v2 = 0.0f;
#pragma unroll
            for (int ns = 0; ns < 4; ns++) {
                const int e = ns * 16 + l15;
                const float val = acc[ms][ns][rr] + bias[hw * HD + e];
                if (sel == 0) {
                    qh[bh_base + (size_t)s * HD + e] = hbits((_Float16)val);
                } else if (sel == 1) {
                    v2 = fmaf(val, val, v2);
                    const size_t kofs = bh_base + (size_t)(s >> 6) * 4096
                                      + swz(s63, e >> 3) + (e & 7);
                    kh[kofs] = hbits((_Float16)val);
                } else {
                    const size_t vofs = bh_base + (size_t)(s >> 6) * 4096
                                      + swz(e, s63 >> 3) + (s63 & 7);
                    vTs[vofs] = hbits((_Float16)val);
                }
            }
            if (sel == 1) {
                v2 += __shfl_xor(v2, 1);
                v2 += __shfl_xor(v2, 2);
                v2 += __shfl_xor(v2, 4);
                v2 += __shfl_xor(v2, 8);
                wmx = fmaxf(wmx, v2);
            }
        }
    }
    if (sel == 1) {
        wmx = fmaxf(wmx, __shfl_xor(wmx, 16));
        wmx = fmaxf(wmx, __shfl_xor(wmx, 32));
        if (lane == 0)
            atomicMax(&kc2[bblk * HH + hw], __float_as_uint(wmx));
    }
}

// ---------------------------------------------------------------------------
// out GEMM: 128x128, BK=64, triple-buffer + depth-2 prefetch + counted vmcnt.
// grid 256 = 1 block/CU: with no co-resident partner, the counted-vmcnt
// pipeline is the only latency cover. 96 KiB LDS.
// ---------------------------------------------------------------------------
__global__ __launch_bounds__(256) void out_gemm(
    const unsigned short* __restrict__ Ctxh, const unsigned short* __restrict__ WoT,
    const float* __restrict__ bo, float* __restrict__ out)
{
    __shared__ __align__(16) unsigned short As[3][16 * 512];
    __shared__ __align__(16) unsigned short Bs[3][16 * 512];

    const int tid = threadIdx.x;
    const int m0 = blockIdx.y * GBM;
    const int n0 = blockIdx.x * GBN;
    const int lane = tid & 63;
    const int w = tid >> 6;
    const int wm = w & 1, wn = w >> 1;
    const int l15 = lane & 15, quad = lane >> 4;

    int g_off[4];
#pragma unroll
    for (int p = 0; p < 4; p++) {
        const int c = p * 4 + w;
        g_off[p] = ((c >> 1) * 16 + (lane & 15)) * DD + (c & 1) * 32 + (lane >> 4) * 8;
    }

    f32x4 acc[4][4];
#pragma unroll
    for (int i = 0; i < 4; i++)
#pragma unroll
        for (int j = 0; j < 4; j++) acc[i][j] = (f32x4){0.f, 0.f, 0.f, 0.f};

    const unsigned short* Abase = Ctxh + (size_t)m0 * DD;
    const unsigned short* Bbase = WoT + (size_t)n0 * DD;

    // prologue: tiles 0,1 -> buffers 0,1; drain once.
#pragma unroll
    for (int p = 0; p < 4; p++) {
        gload_lds16(Abase + g_off[p], &As[0][(p * 4 + w) * 512]);
        gload_lds16(Bbase + g_off[p], &Bs[0][(p * 4 + w) * 512]);
    }
#pragma unroll
    for (int p = 0; p < 4; p++) {
        gload_lds16(Abase + g_off[p] + GBK, &As[1][(p * 4 + w) * 512]);
        gload_lds16(Bbase + g_off[p] + GBK, &Bs[1][(p * 4 + w) * 512]);
    }
    wait0_barrier();

    int cur = 0, pre = 2;
    for (int it = 0; it < NKT; it++) {
        if (it + 2 < NKT) {
            const int kt2 = (it + 2) * GBK;
#pragma unroll
            for (int p = 0; p < 4; p++) {
                gload_lds16(Abase + g_off[p] + kt2, &As[pre][(p * 4 + w) * 512]);
                gload_lds16(Bbase + g_off[p] + kt2, &Bs[pre][(p * 4 + w) * 512]);
            }
        }
#pragma unroll
        for (int ks = 0; ks < 2; ks++) {
            f16x8 af[4], bf[4];
#pragma unroll
            for (int i = 0; i < 4; i++) {
                af[i] = *(const f16x8*)&As[cur][((wm * 4 + i) * 2 + ks) * 512 + lane * 8];
                bf[i] = *(const f16x8*)&Bs[cur][((wn * 4 + i) * 2 + ks) * 512 + lane * 8];
            }
#pragma unroll
            for (int ns = 0; ns < 4; ns++)
#pragma unroll
                for (int ms = 0; ms < 4; ms++)
                    acc[ms][ns] = __builtin_amdgcn_mfma_f32_16x16x32_f16(
                        af[ms], bf[ns], acc[ms][ns], 0, 0, 0);
        }
        if (it < NKT - 2)       wait8_barrier();
        else if (it == NKT - 2) wait0_barrier();
        cur = (cur == 2) ? 0 : cur + 1;
        pre = (pre == 2) ? 0 : pre + 1;
    }

#pragma unroll
    for (int ms = 0; ms < 4; ms++) {
#pragma unroll
        for (int rr = 0; rr < 4; rr++) {
            const size_t m = (size_t)(m0 + wm * 64 + ms * 16 + quad * 4 + rr);
#pragma unroll
            for (int ns = 0; ns < 4; ns++) {
                const int n = n0 + wn * 64 + ns * 16 + l15;
                out[m * DD + n] = acc[ms][ns][rr] + bo[n];
            }
        }
    }
}

// ---------------------------------------------------------------------------
// fp16 MFMA flash attention (S^T), fixed-m softmax, TRIPLE-buffered DMA from
// pre-swizzled K / V^T global tiles, counted vmcnt, l via ones-MFMA.
// LDS 64 KiB -> 2 blocks/CU (grid 512 = 2/CU, unchanged).
// ---------------------------------------------------------------------------
#define TQB 128
#define TKB 64
#define NT (SS / TKB)    // 32
#define C1 0.1803368801111204f   // 0.125 * log2(e)

__global__ __launch_bounds__(256) void attn_mfma(
    const unsigned short* __restrict__ qh, const unsigned short* __restrict__ kh,
    const unsigned short* __restrict__ vTs, const unsigned int* __restrict__ kc2,
    unsigned short* __restrict__ ctxh)
{
    __shared__ __align__(16) unsigned short KL [3][TKB * 64];
    __shared__ __align__(16) unsigned short VtL[3][HD * 64];
    __shared__ __align__(16) unsigned short PsL[4][32 * 64];

    const int tid  = threadIdx.x;
    const int lane = tid & 63;
    const int w    = tid >> 6;
    const int l15  = lane & 15;
    const int quad = lane >> 4;
    const int bh   = blockIdx.y;
    const int q0   = blockIdx.x * TQB;

    const float kfac = sqrtf(__uint_as_float(kc2[bh])) * 1.01f * C1;

    // Q B-frags (lane l15 = q-row, quad = d-octet) + per-lane fixed-m bound
    f16x8 qf[2][2];
    float M2[2];
#pragma unroll
    for (int msub = 0; msub < 2; msub++) {
        const unsigned short* qrow =
            qh + ((size_t)bh * SS + q0 + w * 32 + msub * 16 + l15) * HD;
        float nq2 = 0.0f;
#pragma unroll
        for (int dstep = 0; dstep < 2; dstep++) {
            qf[msub][dstep] = *(const f16x8*)&qrow[dstep * 32 + quad * 8];
#pragma unroll
            for (int j = 0; j < 8; j++) {
                const float x = (float)qf[msub][dstep][j];
                nq2 = fmaf(x, x, nq2);
            }
        }
        nq2 += __shfl_xor(nq2, 16);
        nq2 += __shfl_xor(nq2, 32);
        M2[msub] = sqrtf(nq2) * kfac;
    }

    f16x8 ones;
#pragma unroll
    for (int j = 0; j < 8; j++) ones[j] = (_Float16)1.0f;

    f32x4 o[2][4], lones[2];
#pragma unroll
    for (int ms = 0; ms < 2; ms++) {
        lones[ms] = (f32x4){0.f, 0.f, 0.f, 0.f};
#pragma unroll
        for (int e = 0; e < 4; e++) o[ms][e] = (f32x4){0.f, 0.f, 0.f, 0.f};
    }

    const unsigned short* kb0 = kh  + (size_t)bh * SS * HD;
    const unsigned short* vb0 = vTs + (size_t)bh * SS * HD;

    // prologue: DMA tiles 0,1 into buffers 0,1; drain once.
    gload_lds16(kb0 + tid * 8,        &KL [0][w * 512]);
    gload_lds16(kb0 + 2048 + tid * 8, &KL [0][2048 + w * 512]);
    gload_lds16(vb0 + tid * 8,        &VtL[0][w * 512]);
    gload_lds16(vb0 + 2048 + tid * 8, &VtL[0][2048 + w * 512]);
    gload_lds16(kb0 + 4096 + tid * 8, &KL [1][w * 512]);
    gload_lds16(kb0 + 6144 + tid * 8, &KL [1][2048 + w * 512]);
    gload_lds16(vb0 + 4096 + tid * 8, &VtL[1][w * 512]);
    gload_lds16(vb0 + 6144 + tid * 8, &VtL[1][2048 + w * 512]);
    wait0_barrier();

    int cur = 0, pre = 2;
    for (int t = 0; t < NT; t++) {
        // depth-2 prefetch into buf[(t+2)%3] (reads of that buffer were all
        // consumed by MFMAs before the previous barrier).
        if (t + 2 < NT) {
            const unsigned short* kb = kb0 + (size_t)(t + 2) * 4096;
            const unsigned short* vb = vb0 + (size_t)(t + 2) * 4096;
            gload_lds16(kb + tid * 8,        &KL [pre][w * 512]);
            gload_lds16(kb + 2048 + tid * 8, &KL [pre][2048 + w * 512]);
            gload_lds16(vb + tid * 8,        &VtL[pre][w * 512]);
            gload_lds16(vb + 2048 + tid * 8, &VtL[pre][2048 + w * 512]);
        }

        // ---- scores TRANSPOSED: S^T = K·Q^T; C/D row = key, col = q = l15
        f32x4 sc[2][4];
#pragma unroll
        for (int ksub = 0; ksub < 4; ksub++) {
            const int row = ksub * 16 + l15;
            f16x8 k0 = *(const f16x8*)&KL[cur][swz(row, quad)];
            f16x8 k1 = *(const f16x8*)&KL[cur][swz(row, 4 + quad)];
#pragma unroll
            for (int msub = 0; msub < 2; msub++) {
                f32x4 a = (f32x4){0.f, 0.f, 0.f, 0.f};
                a = __builtin_amdgcn_mfma_f32_16x16x32_f16(k0, qf[msub][0], a, 0, 0, 0);
                a = __builtin_amdgcn_mfma_f32_16x16x32_f16(k1, qf[msub][1], a, 0, 0, 0);
                sc[msub][ksub] = a;
            }
        }

        // ---- fixed-m softmax (per-lane q = l15), packed f16 P
#pragma unroll
        for (int msub = 0; msub < 2; msub++) {
            const int prow = msub * 16 + l15;
#pragma unroll
            for (int ksub = 0; ksub < 4; ksub++) {
                const float p0 = fexp2(fmaf(sc[msub][ksub][0], C1, -M2[msub]));
                const float p1 = fexp2(fmaf(sc[msub][ksub][1], C1, -M2[msub]));
                const float p2 = fexp2(fmaf(sc[msub][ksub][2], C1, -M2[msub]));
                const float p3 = fexp2(fmaf(sc[msub][ksub][3], C1, -M2[msub]));
                *(u16x4*)&PsL[w][swz(prow, ksub * 2 + (quad >> 1)) + (quad & 1) * 4] =
                    pack4(p0, p1, p2, p3);
            }
        }

        // ---- PV + l via ones-MFMA (PsL wave-private: no barrier)
#pragma unroll
        for (int kj = 0; kj < 2; kj++) {
            f16x8 pa[2];
#pragma unroll
            for (int msub = 0; msub < 2; msub++)
                pa[msub] = *(const f16x8*)&PsL[w][swz(msub * 16 + l15, kj * 4 + quad)];
            lones[0] = __builtin_amdgcn_mfma_f32_16x16x32_f16(pa[0], ones, lones[0], 0, 0, 0);
            lones[1] = __builtin_amdgcn_mfma_f32_16x16x32_f16(pa[1], ones, lones[1], 0, 0, 0);
#pragma unroll
            for (int esub = 0; esub < 4; esub++) {
                f16x8 vr = *(const f16x8*)&VtL[cur][swz(esub * 16 + l15, kj * 4 + quad)];
                o[0][esub] = __builtin_amdgcn_mfma_f32_16x16x32_f16(pa[0], vr, o[0][esub], 0, 0, 0);
                o[1][esub] = __builtin_amdgcn_mfma_f32_16x16x32_f16(pa[1], vr, o[1][esub], 0, 0, 0);
            }
        }

        if (t < NT - 2)       wait4_barrier();
        else if (t == NT - 2) wait0_barrier();
        cur = (cur == 2) ? 0 : cur + 1;
        pre = (pre == 2) ? 0 : pre + 1;
    }

    // ---- epilogue: l sits in the same C-layout rows as o — no shuffles
    const int b = bh >> 4;
    const int h = bh & 15;
#pragma unroll
    for (int msub = 0; msub < 2; msub++) {
#pragma unroll
        for (int rr = 0; rr < 4; rr++) {
            const float linv = 1.0f / lones[msub][rr];
            const int row = q0 + w * 32 + msub * 16 + quad * 4 + rr;
#pragma unroll
            for (int esub = 0; esub < 4; esub++) {
                ctxh[((size_t)b * SS + row) * DD + h * HD + esub * 16 + l15] =
                    hbits((_Float16)(o[msub][esub][rr] * linv));
            }
        }
    }
}

// ---------------------------------------------------------------------------
extern "C" void kernel_launch(void* const* d_in, const int* in_sizes, int n_in,
                              void* d_out, int out_size, void* d_ws, size_t ws_size,
                              hipStream_t stream) {
    const float* X  = (const float*)d_in[0];
    const float* Wq = (const float*)d_in[1];
    const float* bq = (const float*)d_in[2];
    const float* Wk = (const float*)d_in[3];
    const float* bk = (const float*)d_in[4];
    const float* Wv = (const float*)d_in[5];
    const float* bv = (const float*)d_in[6];
    const float* Wo = (const float*)d_in[7];
    const float* bo = (const float*)d_in[8];
    float* out = (float*)d_out;

    // ws: Xh | WT(4096 rows) | qh | kh(swz) | vTs(swz) | ctxh | kc2
    const size_t NB2 = (size_t)4096 * 1024 * 2;   // 8388608 B
    unsigned char* w8 = (unsigned char*)d_ws;
    unsigned short* Xh   = (unsigned short*)(w8);
    unsigned short* WT   = (unsigned short*)(w8 + NB2);
    unsigned short* qh   = (unsigned short*)(w8 + 2 * NB2);
    unsigned short* kh   = (unsigned short*)(w8 + 3 * NB2);
    unsigned short* vTs  = (unsigned short*)(w8 + 4 * NB2);
    unsigned short* ctxh = (unsigned short*)(w8 + 5 * NB2);
    unsigned int*   kc2  = (unsigned int*)(w8 + 6 * NB2);
    unsigned short* WoT  = WT + (size_t)3072 * 1024;

    (void)hipMemsetAsync(kc2, 0, BB * HH * sizeof(unsigned int), stream);

    // 0) convert X + transpose/convert weights to fp16
    prep_convert<<<dim3(3072), 256, 0, stream>>>(X, Wq, Wk, Wv, Wo, Xh, WT);

    // 1) fused QKV projection (BK=32, 3-buf counted-vmcnt, 3 blocks/CU)
    qkv_gemm<<<dim3(3072 / GBN, 4096 / GBM), 256, 0, stream>>>(
        Xh, WT, bq, bk, bv, qh, kh, vTs, kc2);

    // 2) MFMA flash attention (S^T, fixed-m softmax, 3-buf counted-vmcnt)
    attn_mfma<<<dim3(SS / TQB, BB * HH), 256, 0, stream>>>(qh, kh, vTs, kc2, ctxh);

    // 3) output projection (3-buf counted-vmcnt)
    out_gemm<<<dim3(1024 / GBN, 4096 / GBM), 256, 0, stream>>>(ctxh, WoT, bo, out);
}